// Round 7
// baseline (276.217 us; speedup 1.0000x reference)
//
#include <hip/hip_runtime.h>
#include <hip/hip_bf16.h>

// GCN 2-layer: h1' = relu(S·(x@w1) + b1); out = S·(h1'@w2) + b2
// Two-level coalesced counting sort -> exact CSR by dst; wave-per-node
// register-accumulating gather (direct per-lane rec loads, 16 lanes/edge);
// bf16 MFMA GEMMs with LDS-staged coalesced C stores.
// N=100000, E=1600000, IN=128, HID=64, OUT=64.
//
// Perf journal:
//  R1 scatter+atomics: 2862us (atomic-RMW bound, WRITE 1.6GB)
//  R2 CSR+wave-gather: 633us; R3 +4-edge gather, 64x64 gemm: 466us
//  R4 bucket-LDS-agg: 1587us REGRESSION (6K waves, latency-starved)
//  R5 two-level sort: 326us; R6 MFMA gemms + ushort8 gather: 262us
//     (gather 48us: VALUBusy 51%, shfl=ds_bpermute is the hidden cost)
//  R7 (this): shfl-free gather (direct rec loads), NB1 391, LDS C-store.

#define N_NODES 100000
#define N_EDGES 1600000
#define NB1     391     // coarse buckets of 256 dst nodes (dst>>8)
#define T1      4096    // pass-1 tile (edges per block)
#define NT1     391     // ceil(E/T1)

typedef unsigned short ushort_t;
typedef unsigned int uint_t;
typedef __attribute__((ext_vector_type(8))) short bf16x8;
typedef __attribute__((ext_vector_type(4))) float floatx4;
typedef __attribute__((ext_vector_type(8))) ushort_t ushort8v;

static __device__ __forceinline__ float bf2f(ushort_t h) {
    return __uint_as_float(((uint_t)h) << 16);
}
static __device__ __forceinline__ ushort_t f2bf(float f) {
    uint_t u = __float_as_uint(f);
    u = (u + 0x7FFF + ((u >> 16) & 1)) >> 16;   // RNE
    return (ushort_t)u;
}

// ---------------------------------------------------------------------------
// Sort stage 1: per-tile coarse-bucket histogram.
// ---------------------------------------------------------------------------
__global__ __launch_bounds__(512) void k_count1(
    const int* __restrict__ dst, int* __restrict__ counts, int E)
{
    __shared__ int cnt[NB1];
    const int t = threadIdx.x;
    if (t < NB1) cnt[t] = 0;
    __syncthreads();
    const int e0 = blockIdx.x * T1;
    const int e1 = min(E, e0 + T1);
    for (int e = e0 + t; e < e1; e += 512)
        atomicAdd(&cnt[dst[e] >> 8], 1);
    __syncthreads();
    if (t < NB1) counts[(size_t)blockIdx.x * NB1 + t] = cnt[t];
}

// Stage 2: per-bucket exclusive scan over tiles. offs[tile][k], ctot[k].
__global__ __launch_bounds__(512) void k_cscan(
    const int* __restrict__ counts, int* __restrict__ offs,
    int* __restrict__ ctot)
{
    __shared__ int s[512];
    const int t = threadIdx.x, k = blockIdx.x;
    const int v = (t < NT1) ? counts[(size_t)t * NB1 + k] : 0;
    s[t] = v;
    #pragma unroll
    for (int off = 1; off < 512; off <<= 1) {
        __syncthreads();
        int a = (t >= off) ? s[t - off] : 0;
        __syncthreads();
        s[t] += a;
    }
    __syncthreads();
    if (t < NT1) offs[(size_t)t * NB1 + k] = s[t] - v;
    if (t == 511) ctot[k] = s[511];
}

// Stage 3: exclusive scan of bucket totals -> bucket bases.
__global__ __launch_bounds__(512) void k_tscan(
    const int* __restrict__ ctot, int* __restrict__ cbase)
{
    __shared__ int s[512];
    const int t = threadIdx.x;
    const int v = (t < NB1) ? ctot[t] : 0;
    s[t] = v;
    #pragma unroll
    for (int off = 1; off < 512; off <<= 1) {
        __syncthreads();
        int a = (t >= off) ? s[t - off] : 0;
        __syncthreads();
        s[t] += a;
    }
    __syncthreads();
    if (t < NB1) cbase[t] = s[t] - v;
}

// ---------------------------------------------------------------------------
// Stage 4 (pass 1): LDS multisplit into 391 coarse buckets; write bucket-
// grouped runs (~10 recs). rec.x = (dst&255)<<17 | src (src < 2^17).
// ---------------------------------------------------------------------------
__global__ __launch_bounds__(512) void k_pass1(
    const int* __restrict__ src, const int* __restrict__ dst,
    const float* __restrict__ ew, const int* __restrict__ offs,
    const int* __restrict__ cbase, int2* __restrict__ recs1, int E)
{
    __shared__ int cnt[NB1], start[NB1], cursor[NB1], gb[NB1];
    __shared__ int s[512];
    __shared__ int2 stg[T1];            // 32 KB
    __shared__ ushort_t sb[T1];         // 8 KB
    const int t = threadIdx.x, b = blockIdx.x;

    if (t < NB1) cnt[t] = 0;
    __syncthreads();
    const int e0 = b * T1;
    const int e1 = min(E, e0 + T1);
    for (int e = e0 + t; e < e1; e += 512)
        atomicAdd(&cnt[dst[e] >> 8], 1);
    __syncthreads();
    const int v = (t < NB1) ? cnt[t] : 0;
    s[t] = v;
    #pragma unroll
    for (int off = 1; off < 512; off <<= 1) {
        __syncthreads();
        int a = (t >= off) ? s[t - off] : 0;
        __syncthreads();
        s[t] += a;
    }
    __syncthreads();
    if (t < NB1) {
        int st = s[t] - v;
        start[t]  = st;
        cursor[t] = st;
        gb[t]     = cbase[t] + offs[(size_t)b * NB1 + t];
    }
    __syncthreads();
    for (int e = e0 + t; e < e1; e += 512) {
        int d  = dst[e];
        int bk = d >> 8;
        int p  = atomicAdd(&cursor[bk], 1);
        int2 r;
        r.x = ((d & 255) << 17) | src[e];
        r.y = __float_as_int(ew[e]);
        stg[p] = r;
        sb[p]  = (ushort_t)bk;
    }
    __syncthreads();
    const int n = e1 - e0;
    for (int i = t; i < n; i += 512) {
        int bk = sb[i];
        recs1[gb[bk] + (i - start[bk])] = stg[i];
    }
}

// ---------------------------------------------------------------------------
// Pass 2: one block per coarse bucket (256 nodes) -> exact per-node CSR in
// the bucket's exclusive ~33 KB window. nodeinfo[n] = {start, cnt}.
// ---------------------------------------------------------------------------
__global__ __launch_bounds__(256) void k_pass2(
    const int2* __restrict__ recs1, const int* __restrict__ cbase,
    const int* __restrict__ ctot, int2* __restrict__ recs2,
    int2* __restrict__ nodeinfo, int N)
{
    __shared__ int cnt[256];
    __shared__ int s[256];
    __shared__ int cursor[256];
    const int t = threadIdx.x, b = blockIdx.x;
    const int lo = cbase[b];
    const int hi = lo + ctot[b];

    cnt[t] = 0;
    __syncthreads();
    for (int j = lo + t; j < hi; j += 256)
        atomicAdd(&cnt[((uint_t)recs1[j].x) >> 17], 1);
    __syncthreads();
    const int v = cnt[t];
    s[t] = v;
    #pragma unroll
    for (int off = 1; off < 256; off <<= 1) {
        __syncthreads();
        int a = (t >= off) ? s[t - off] : 0;
        __syncthreads();
        s[t] += a;
    }
    __syncthreads();
    const int stl = s[t] - v;
    cursor[t] = stl;
    const int ng = b * 256 + t;
    if (ng < N) {
        int2 ni; ni.x = lo + stl; ni.y = v;
        nodeinfo[ng] = ni;
    }
    __syncthreads();
    for (int j = lo + t; j < hi; j += 256) {
        int2 r = recs1[j];
        int dl = ((uint_t)r.x) >> 17;
        int p  = atomicAdd(&cursor[dl], 1);
        int2 o;
        o.x = r.x & 0x1FFFF;
        o.y = r.y;
        recs2[lo + p] = o;
    }
}

// ---------------------------------------------------------------------------
// MFMA GEMM1: Y[bf16, N x 64] = bf16(X[f32, N x 128]) @ bf16(W[128 x 64])
// 64 rows/block, 4 waves. LDS rows padded (stride 136/72 bf16).
// A[m=lane&15][k=quad*8+j]; B[k][n] staged transposed; C row=quad*4+r,
// col=lane&15 -> staged through LDS for coalesced ushort8 stores.
// ---------------------------------------------------------------------------
__global__ __launch_bounds__(256) void k_gemm1(
    const float* __restrict__ X, const float* __restrict__ W,
    ushort_t* __restrict__ Y, int N)
{
    __shared__ ushort_t sA[64 * 136];   // 17408 B; reused for C stage
    __shared__ ushort_t sB[64 * 136];
    const int tid  = threadIdx.x;
    const int row0 = blockIdx.x * 64;

    for (int i = tid; i < 64 * 32; i += 256) {         // A: 64 rows x 32 f4
        int r = i >> 5, c4 = (i & 31) * 4;
        int rg = row0 + r; if (rg > N - 1) rg = N - 1;
        float4 v = *(const float4*)(X + (size_t)rg * 128 + c4);
        ushort4 pk = make_ushort4(f2bf(v.x), f2bf(v.y), f2bf(v.z), f2bf(v.w));
        *(ushort4*)(sA + r * 136 + c4) = pk;
    }
    for (int i = tid; i < 128 * 16; i += 256) {        // B: 128 rows x 16 f4
        int k = i >> 4, n4 = (i & 15) * 4;
        float4 v = *(const float4*)(W + (size_t)k * 64 + n4);
        sB[(n4 + 0) * 136 + k] = f2bf(v.x);
        sB[(n4 + 1) * 136 + k] = f2bf(v.y);
        sB[(n4 + 2) * 136 + k] = f2bf(v.z);
        sB[(n4 + 3) * 136 + k] = f2bf(v.w);
    }
    __syncthreads();

    const int wid = tid >> 6, lane = tid & 63;
    const int m = lane & 15, quad = lane >> 4;
    floatx4 acc[4] = {};

    #pragma unroll
    for (int ks = 0; ks < 4; ++ks) {
        bf16x8 a = *(const bf16x8*)(sA + (wid * 16 + m) * 136 + ks * 32 + quad * 8);
        #pragma unroll
        for (int nt = 0; nt < 4; ++nt) {
            bf16x8 bfr = *(const bf16x8*)(sB + (nt * 16 + m) * 136 + ks * 32 + quad * 8);
            acc[nt] = __builtin_amdgcn_mfma_f32_16x16x32_bf16(a, bfr, acc[nt], 0, 0, 0);
        }
    }
    __syncthreads();                    // all sA reads done
    #pragma unroll
    for (int nt = 0; nt < 4; ++nt)
        #pragma unroll
        for (int r = 0; r < 4; ++r)
            sA[(wid * 16 + quad * 4 + r) * 72 + nt * 16 + m] = f2bf(acc[nt][r]);
    __syncthreads();
    for (int i = tid; i < 64 * 8; i += 256) {          // coalesced C store
        int rr = i >> 3, c8 = (i & 7) * 8;
        int rg = row0 + rr;
        if (rg < N)
            *(ushort8v*)(Y + (size_t)rg * 64 + c8) =
                *(const ushort8v*)(sA + rr * 72 + c8);
    }
}

// ---------------------------------------------------------------------------
// MFMA GEMM2: Y[bf16, N x 64] = X[bf16, N x 64] @ bf16(W[64 x 64])
// ---------------------------------------------------------------------------
__global__ __launch_bounds__(256) void k_gemm2(
    const ushort_t* __restrict__ X, const float* __restrict__ W,
    ushort_t* __restrict__ Y, int N)
{
    __shared__ ushort_t sA[64 * 72];    // 9216 B; reused for C stage
    __shared__ ushort_t sB[64 * 72];
    const int tid  = threadIdx.x;
    const int row0 = blockIdx.x * 64;

    for (int i = tid; i < 64 * 16; i += 256) {         // A: 64 rows x 16 us4
        int r = i >> 4, c4 = (i & 15) * 4;
        int rg = row0 + r; if (rg > N - 1) rg = N - 1;
        *(ushort4*)(sA + r * 72 + c4) =
            *(const ushort4*)(X + (size_t)rg * 64 + c4);
    }
    for (int i = tid; i < 64 * 16; i += 256) {         // B: 64 rows x 16 f4
        int k = i >> 4, n4 = (i & 15) * 4;
        float4 v = *(const float4*)(W + (size_t)k * 64 + n4);
        sB[(n4 + 0) * 72 + k] = f2bf(v.x);
        sB[(n4 + 1) * 72 + k] = f2bf(v.y);
        sB[(n4 + 2) * 72 + k] = f2bf(v.z);
        sB[(n4 + 3) * 72 + k] = f2bf(v.w);
    }
    __syncthreads();

    const int wid = tid >> 6, lane = tid & 63;
    const int m = lane & 15, quad = lane >> 4;
    floatx4 acc[4] = {};

    #pragma unroll
    for (int ks = 0; ks < 2; ++ks) {
        bf16x8 a = *(const bf16x8*)(sA + (wid * 16 + m) * 72 + ks * 32 + quad * 8);
        #pragma unroll
        for (int nt = 0; nt < 4; ++nt) {
            bf16x8 bfr = *(const bf16x8*)(sB + (nt * 16 + m) * 72 + ks * 32 + quad * 8);
            acc[nt] = __builtin_amdgcn_mfma_f32_16x16x32_bf16(a, bfr, acc[nt], 0, 0, 0);
        }
    }
    __syncthreads();
    #pragma unroll
    for (int nt = 0; nt < 4; ++nt)
        #pragma unroll
        for (int r = 0; r < 4; ++r)
            sA[(wid * 16 + quad * 4 + r) * 72 + nt * 16 + m] = f2bf(acc[nt][r]);
    __syncthreads();
    for (int i = tid; i < 64 * 8; i += 256) {
        int rr = i >> 3, c8 = (i & 7) * 8;
        int rg = row0 + rr;
        if (rg < N)
            *(ushort8v*)(Y + (size_t)rg * 64 + c8) =
                *(const ushort8v*)(sA + rr * 72 + c8);
    }
}

// ---------------------------------------------------------------------------
// Gather-reduce: one wave per node; group g = lane>>4 handles edge k*4+g;
// 16 lanes x ushort4 per edge. Each lane loads its own record (16 lanes
// share one rec -> coalesced 32B/wave from a sequential L1-hot region).
// No shfl broadcasts; final reduce = 8 shfl. No atomics.
// ---------------------------------------------------------------------------
template<bool RELU, bool OUT_BF16>
__global__ __launch_bounds__(256) void k_gather(
    const ushort_t* __restrict__ H, const int2* __restrict__ recs,
    const int2* __restrict__ nodeinfo, const float* __restrict__ bias,
    void* __restrict__ out)
{
    const int wid  = threadIdx.x >> 6;
    const int lane = threadIdx.x & 63;
    const int n    = blockIdx.x * 4 + wid;   // grid = N/4 exactly

    const int2 ni   = nodeinfo[n];
    const int start = ni.x;
    const int cnt   = ni.y;
    const int end   = start + cnt;
    const int g     = lane >> 4;          // edge slot in round
    const int c4    = (lane & 15) * 4;    // channel base
    const int trip  = (cnt + 3) >> 2;

    float a0 = 0.f, a1 = 0.f, a2 = 0.f, a3 = 0.f;
    int j = start + g;
    #pragma unroll 2
    for (int k = 0; k < trip; ++k, j += 4) {
        int jc = (j < end) ? j : (end - 1);     // valid: trip>0 => end>start
        int2 r = recs[jc];
        float w = (j < end) ? __int_as_float(r.y) : 0.f;
        ushort4 hv = *(const ushort4*)(H + (size_t)r.x * 64 + c4);
        a0 = fmaf(w, bf2f(hv.x), a0);
        a1 = fmaf(w, bf2f(hv.y), a1);
        a2 = fmaf(w, bf2f(hv.z), a2);
        a3 = fmaf(w, bf2f(hv.w), a3);
    }
    // reduce across the 4 groups (lanes l, l+16, l+32, l+48)
    a0 += __shfl_down(a0, 32); a1 += __shfl_down(a1, 32);
    a2 += __shfl_down(a2, 32); a3 += __shfl_down(a3, 32);
    a0 += __shfl_down(a0, 16); a1 += __shfl_down(a1, 16);
    a2 += __shfl_down(a2, 16); a3 += __shfl_down(a3, 16);

    if (lane < 16) {
        float4 bv = *(const float4*)(bias + c4);
        float v0 = a0 + bv.x, v1 = a1 + bv.y, v2 = a2 + bv.z, v3 = a3 + bv.w;
        if (RELU) {
            v0 = fmaxf(v0, 0.f); v1 = fmaxf(v1, 0.f);
            v2 = fmaxf(v2, 0.f); v3 = fmaxf(v3, 0.f);
        }
        if (OUT_BF16) {
            ushort4 pk = make_ushort4(f2bf(v0), f2bf(v1), f2bf(v2), f2bf(v3));
            *(ushort4*)((ushort_t*)out + (size_t)n * 64 + c4) = pk;
        } else {
            *(float4*)((float*)out + (size_t)n * 64 + c4) =
                make_float4(v0, v1, v2, v3);
        }
    }
}

// ---------------------------------------------------------------------------
extern "C" void kernel_launch(void* const* d_in, const int* in_sizes, int n_in,
                              void* d_out, int out_size, void* d_ws, size_t ws_size,
                              hipStream_t stream) {
    const float* x   = (const float*)d_in[0];
    const int*   ei  = (const int*)  d_in[1];
    const float* ew  = (const float*)d_in[2];
    const float* w1  = (const float*)d_in[3];
    const float* b1  = (const float*)d_in[4];
    const float* w2  = (const float*)d_in[5];
    const float* b2  = (const float*)d_in[6];
    float* out = (float*)d_out;

    const int N = N_NODES, E = N_EDGES;
    const int* src = ei;
    const int* dst = ei + E;

    char* p = (char*)d_ws;
    ushort_t* bufA   = (ushort_t*)p;  p += (size_t)N_NODES * 64 * 2;   // 12.8MB: h1 / h2
    int2*     recs2  = (int2*)p;      p += (size_t)N_EDGES * 8;        // 12.8MB: exact CSR
    // recs1 (pass-1 output) aliases bufB: dead before gather1 writes bufB.
    int2*     recs1  = (int2*)p;
    ushort_t* bufB   = (ushort_t*)p;  p += (size_t)N_EDGES * 8;        // 12.8MB
    int*      counts = (int*)p;       p += (size_t)NT1 * NB1 * 4;
    int*      offs   = (int*)p;       p += (size_t)NT1 * NB1 * 4;
    int*      ctot   = (int*)p;       p += 2048;
    int*      cbase  = (int*)p;       p += 2048;
    int2*     ninfo  = (int2*)p;      p += (size_t)N_NODES * 8;

    // ---- two-level sort to exact CSR
    k_count1<<<NT1, 512, 0, stream>>>(dst, counts, E);
    k_cscan <<<NB1, 512, 0, stream>>>(counts, offs, ctot);
    k_tscan <<<1,   512, 0, stream>>>(ctot, cbase);
    k_pass1 <<<NT1, 512, 0, stream>>>(src, dst, ew, offs, cbase, recs1, E);
    k_pass2 <<<NB1, 256, 0, stream>>>(recs1, cbase, ctot, recs2, ninfo, N);

    // ---- layer 1
    k_gemm1<<<(N + 63) / 64, 256, 0, stream>>>(x, w1, bufA, N);
    k_gather<true, true><<<N / 4, 256, 0, stream>>>(bufA, recs2, ninfo, b1, bufB);

    // ---- layer 2
    k_gemm2<<<(N + 63) / 64, 256, 0, stream>>>(bufB, w2, bufA, N);
    k_gather<false, false><<<N / 4, 256, 0, stream>>>(bufA, recs2, ninfo, b2, out);
}

// Round 8
// 247.323 us; speedup vs baseline: 1.1168x; 1.1168x over previous
//
#include <hip/hip_runtime.h>
#include <hip/hip_bf16.h>

// GCN 2-layer: h1' = relu(S·(x@w1) + b1); out = S·(h1'@w2) + b2
// Single-pass bucket multisplit (global cursor reservation) -> exact CSR by
// dst; gather = 2 nodes/wave, 16 lanes x ushort4/edge, 64-wide rec preload
// + shfl broadcast (max in-flight loads). bf16 MFMA GEMMs.
// N=100000, E=1600000, IN=128, HID=64, OUT=64.
//
// Perf journal:
//  R1 scatter+atomics: 2862us (atomic-RMW bound, WRITE 1.6GB)
//  R2 CSR+wave-gather: 633us; R3 +4-edge gather, 64x64 gemm: 466us
//  R4 bucket-LDS-agg: 1587us REGRESSION (6K waves, latency-starved)
//  R5 two-level sort: 326us; R6 MFMA gemms + ushort8 gather: 262us
//  R7 shfl-free gather: 276us REGRESSION (rec->H dependent chain, MLP 2
//     vs R6's preload+broadcast MLP 8; VALUBusy 51->35 but slower)
//  R8 (this): R6 broadcast + 2 nodes/wave (2x MLP), 16-lane groups
//     (fewer reduce shfls), single-pass sort (3 launches + dst pass gone).

#define N_NODES 100000
#define N_EDGES 1600000
#define NB1     391     // coarse buckets of 256 dst nodes (dst>>8)
#define T1      4096    // pass-1 tile (edges per block)
#define NT1     391     // ceil(E/T1)
#define CAP1    4706    // per-bucket slack: mean 4092 + 9.6 sigma

typedef unsigned short ushort_t;
typedef unsigned int uint_t;
typedef __attribute__((ext_vector_type(8))) short bf16x8;
typedef __attribute__((ext_vector_type(4))) float floatx4;
typedef __attribute__((ext_vector_type(8))) ushort_t ushort8v;

static __device__ __forceinline__ float bf2f(ushort_t h) {
    return __uint_as_float(((uint_t)h) << 16);
}
static __device__ __forceinline__ ushort_t f2bf(float f) {
    uint_t u = __float_as_uint(f);
    u = (u + 0x7FFF + ((u >> 16) & 1)) >> 16;   // RNE
    return (ushort_t)u;
}

// ---------------------------------------------------------------------------
// gcursor[b] = b * CAP1  (bucket window bases)
// ---------------------------------------------------------------------------
__global__ __launch_bounds__(512) void k_init(int* __restrict__ gcursor)
{
    int t = threadIdx.x;
    if (t < NB1) gcursor[t] = t * CAP1;
}

// ---------------------------------------------------------------------------
// Pass 1 (single-pass multisplit): per-tile LDS histogram of 391 buckets,
// reserve global space via one atomicAdd per (tile,bucket), bin in LDS,
// stream out bucket-grouped runs. rec.x = (dst&255)<<17 | src (src < 2^17).
// ---------------------------------------------------------------------------
__global__ __launch_bounds__(512) void k_pass1(
    const int* __restrict__ src, const int* __restrict__ dst,
    const float* __restrict__ ew, int* __restrict__ gcursor,
    int2* __restrict__ recs1, int E)
{
    __shared__ int cnt[NB1], start[NB1], cursor[NB1], gb[NB1];
    __shared__ int s[512];
    __shared__ int2 stg[T1];            // 32 KB
    __shared__ ushort_t sb[T1];         // 8 KB
    const int t = threadIdx.x, b = blockIdx.x;

    if (t < NB1) cnt[t] = 0;
    __syncthreads();
    const int e0 = b * T1;
    const int e1 = min(E, e0 + T1);
    for (int e = e0 + t; e < e1; e += 512)
        atomicAdd(&cnt[dst[e] >> 8], 1);
    __syncthreads();
    const int v = (t < NB1) ? cnt[t] : 0;
    s[t] = v;
    #pragma unroll
    for (int off = 1; off < 512; off <<= 1) {
        __syncthreads();
        int a = (t >= off) ? s[t - off] : 0;
        __syncthreads();
        s[t] += a;
    }
    __syncthreads();
    if (t < NB1) {
        int st = s[t] - v;
        start[t]  = st;
        cursor[t] = st;
        gb[t]     = atomicAdd(&gcursor[t], v);   // device-scope reservation
    }
    __syncthreads();
    for (int e = e0 + t; e < e1; e += 512) {
        int d  = dst[e];
        int bk = d >> 8;
        int p  = atomicAdd(&cursor[bk], 1);
        int2 r;
        r.x = ((d & 255) << 17) | src[e];
        r.y = __float_as_int(ew[e]);
        stg[p] = r;
        sb[p]  = (ushort_t)bk;
    }
    __syncthreads();
    const int n = e1 - e0;
    for (int i = t; i < n; i += 512) {
        int bk = sb[i];
        recs1[gb[bk] + (i - start[bk])] = stg[i];
    }
}

// ---------------------------------------------------------------------------
// Pass 2: one block per coarse bucket (256 nodes) -> exact per-node CSR in
// the bucket's exclusive window [b*CAP1, gcursor[b]). ninfo[n]={start,cnt}.
// ---------------------------------------------------------------------------
__global__ __launch_bounds__(256) void k_pass2(
    const int2* __restrict__ recs1, const int* __restrict__ gcursor,
    int2* __restrict__ recs2, int2* __restrict__ nodeinfo, int N)
{
    __shared__ int cnt[256];
    __shared__ int s[256];
    __shared__ int cursor[256];
    const int t = threadIdx.x, b = blockIdx.x;
    const int lo = b * CAP1;
    const int hi = gcursor[b];

    cnt[t] = 0;
    __syncthreads();
    for (int j = lo + t; j < hi; j += 256)
        atomicAdd(&cnt[((uint_t)recs1[j].x) >> 17], 1);
    __syncthreads();
    const int v = cnt[t];
    s[t] = v;
    #pragma unroll
    for (int off = 1; off < 256; off <<= 1) {
        __syncthreads();
        int a = (t >= off) ? s[t - off] : 0;
        __syncthreads();
        s[t] += a;
    }
    __syncthreads();
    const int stl = s[t] - v;
    cursor[t] = stl;
    const int ng = b * 256 + t;
    if (ng < N) {
        int2 ni; ni.x = lo + stl; ni.y = v;
        nodeinfo[ng] = ni;
    }
    __syncthreads();
    for (int j = lo + t; j < hi; j += 256) {
        int2 r = recs1[j];
        int dl = ((uint_t)r.x) >> 17;
        int p  = atomicAdd(&cursor[dl], 1);
        int2 o;
        o.x = r.x & 0x1FFFF;
        o.y = r.y;
        recs2[lo + p] = o;
    }
}

// ---------------------------------------------------------------------------
// MFMA GEMM1: Y[bf16, N x 64] = bf16(X[f32, N x 128]) @ bf16(W[128 x 64])
// 64 rows/block, 4 waves. LDS rows padded (stride 136/72 bf16).
// A[m=lane&15][k=quad*8+j]; B staged transposed; C row=quad*4+r,
// col=lane&15 -> staged through LDS for coalesced ushort8 stores.
// ---------------------------------------------------------------------------
__global__ __launch_bounds__(256) void k_gemm1(
    const float* __restrict__ X, const float* __restrict__ W,
    ushort_t* __restrict__ Y, int N)
{
    __shared__ ushort_t sA[64 * 136];   // 17408 B; reused for C stage
    __shared__ ushort_t sB[64 * 136];
    const int tid  = threadIdx.x;
    const int row0 = blockIdx.x * 64;

    for (int i = tid; i < 64 * 32; i += 256) {         // A: 64 rows x 32 f4
        int r = i >> 5, c4 = (i & 31) * 4;
        int rg = row0 + r; if (rg > N - 1) rg = N - 1;
        float4 v = *(const float4*)(X + (size_t)rg * 128 + c4);
        ushort4 pk = make_ushort4(f2bf(v.x), f2bf(v.y), f2bf(v.z), f2bf(v.w));
        *(ushort4*)(sA + r * 136 + c4) = pk;
    }
    for (int i = tid; i < 128 * 16; i += 256) {        // B: 128 rows x 16 f4
        int k = i >> 4, n4 = (i & 15) * 4;
        float4 v = *(const float4*)(W + (size_t)k * 64 + n4);
        sB[(n4 + 0) * 136 + k] = f2bf(v.x);
        sB[(n4 + 1) * 136 + k] = f2bf(v.y);
        sB[(n4 + 2) * 136 + k] = f2bf(v.z);
        sB[(n4 + 3) * 136 + k] = f2bf(v.w);
    }
    __syncthreads();

    const int wid = tid >> 6, lane = tid & 63;
    const int m = lane & 15, quad = lane >> 4;
    floatx4 acc[4] = {};

    #pragma unroll
    for (int ks = 0; ks < 4; ++ks) {
        bf16x8 a = *(const bf16x8*)(sA + (wid * 16 + m) * 136 + ks * 32 + quad * 8);
        #pragma unroll
        for (int nt = 0; nt < 4; ++nt) {
            bf16x8 bfr = *(const bf16x8*)(sB + (nt * 16 + m) * 136 + ks * 32 + quad * 8);
            acc[nt] = __builtin_amdgcn_mfma_f32_16x16x32_bf16(a, bfr, acc[nt], 0, 0, 0);
        }
    }
    __syncthreads();                    // all sA reads done
    #pragma unroll
    for (int nt = 0; nt < 4; ++nt)
        #pragma unroll
        for (int r = 0; r < 4; ++r)
            sA[(wid * 16 + quad * 4 + r) * 72 + nt * 16 + m] = f2bf(acc[nt][r]);
    __syncthreads();
    for (int i = tid; i < 64 * 8; i += 256) {          // coalesced C store
        int rr = i >> 3, c8 = (i & 7) * 8;
        int rg = row0 + rr;
        if (rg < N)
            *(ushort8v*)(Y + (size_t)rg * 64 + c8) =
                *(const ushort8v*)(sA + rr * 72 + c8);
    }
}

// ---------------------------------------------------------------------------
// MFMA GEMM2: Y[bf16, N x 64] = X[bf16, N x 64] @ bf16(W[64 x 64])
// ---------------------------------------------------------------------------
__global__ __launch_bounds__(256) void k_gemm2(
    const ushort_t* __restrict__ X, const float* __restrict__ W,
    ushort_t* __restrict__ Y, int N)
{
    __shared__ ushort_t sA[64 * 72];    // 9216 B; reused for C stage
    __shared__ ushort_t sB[64 * 72];
    const int tid  = threadIdx.x;
    const int row0 = blockIdx.x * 64;

    for (int i = tid; i < 64 * 16; i += 256) {         // A: 64 rows x 16 us4
        int r = i >> 4, c4 = (i & 15) * 4;
        int rg = row0 + r; if (rg > N - 1) rg = N - 1;
        *(ushort4*)(sA + r * 72 + c4) =
            *(const ushort4*)(X + (size_t)rg * 64 + c4);
    }
    for (int i = tid; i < 64 * 16; i += 256) {         // B: 64 rows x 16 f4
        int k = i >> 4, n4 = (i & 15) * 4;
        float4 v = *(const float4*)(W + (size_t)k * 64 + n4);
        sB[(n4 + 0) * 72 + k] = f2bf(v.x);
        sB[(n4 + 1) * 72 + k] = f2bf(v.y);
        sB[(n4 + 2) * 72 + k] = f2bf(v.z);
        sB[(n4 + 3) * 72 + k] = f2bf(v.w);
    }
    __syncthreads();

    const int wid = tid >> 6, lane = tid & 63;
    const int m = lane & 15, quad = lane >> 4;
    floatx4 acc[4] = {};

    #pragma unroll
    for (int ks = 0; ks < 2; ++ks) {
        bf16x8 a = *(const bf16x8*)(sA + (wid * 16 + m) * 72 + ks * 32 + quad * 8);
        #pragma unroll
        for (int nt = 0; nt < 4; ++nt) {
            bf16x8 bfr = *(const bf16x8*)(sB + (nt * 16 + m) * 72 + ks * 32 + quad * 8);
            acc[nt] = __builtin_amdgcn_mfma_f32_16x16x32_bf16(a, bfr, acc[nt], 0, 0, 0);
        }
    }
    __syncthreads();
    #pragma unroll
    for (int nt = 0; nt < 4; ++nt)
        #pragma unroll
        for (int r = 0; r < 4; ++r)
            sA[(wid * 16 + quad * 4 + r) * 72 + nt * 16 + m] = f2bf(acc[nt][r]);
    __syncthreads();
    for (int i = tid; i < 64 * 8; i += 256) {
        int rr = i >> 3, c8 = (i & 7) * 8;
        int rg = row0 + rr;
        if (rg < N)
            *(ushort8v*)(Y + (size_t)rg * 64 + c8) =
                *(const ushort8v*)(sA + rr * 72 + c8);
    }
}

// ---------------------------------------------------------------------------
// Gather-reduce: TWO nodes per wave (independent load chains -> 2x MLP).
// Per node: preload 64 recs in one coalesced load, shfl-broadcast; group
// g = lane>>4 handles edge jj+g; 16 lanes x ushort4 per edge. Epilogue:
// 4 accs x 2 shfl levels per node. No atomics.
// ---------------------------------------------------------------------------
template<bool RELU, bool OUT_BF16>
__global__ __launch_bounds__(256) void k_gather(
    const ushort_t* __restrict__ H, const int2* __restrict__ recs,
    const int2* __restrict__ nodeinfo, const float* __restrict__ bias,
    void* __restrict__ out)
{
    const int wid  = threadIdx.x >> 6;
    const int lane = threadIdx.x & 63;
    const int n0   = (blockIdx.x * 4 + wid) * 2;   // grid = N/8 exactly
    const int n1   = n0 + 1;

    const int2 niA = nodeinfo[n0];
    const int2 niB = nodeinfo[n1];
    int baseA = niA.x; const int endA = niA.x + niA.y;
    int baseB = niB.x; const int endB = niB.x + niB.y;

    const int g  = lane >> 4;           // edge slot in round
    const int c4 = (lane & 15) * 4;     // channel base

    float a0 = 0.f, a1 = 0.f, a2 = 0.f, a3 = 0.f;
    float b0 = 0.f, b1 = 0.f, b2 = 0.f, b3 = 0.f;

    while (baseA < endA || baseB < endB) {
        int mA = endA - baseA; if (mA > 64) mA = 64;
        int mB = endB - baseB; if (mB > 64) mB = 64;
        int2 rA = (mA > 0) ? recs[baseA + (lane < mA ? lane : mA - 1)]
                           : make_int2(0, 0);
        int2 rB = (mB > 0) ? recs[baseB + (lane < mB ? lane : mB - 1)]
                           : make_int2(0, 0);
        float wAf = __int_as_float(rA.y);
        float wBf = __int_as_float(rB.y);
        int mm = mA > mB ? mA : mB;
        #pragma unroll 2
        for (int jj = 0; jj < mm; jj += 4) {
            int idx = jj + g;
            int   sA = __shfl(rA.x, idx);
            float wA = __shfl(wAf, idx);
            int   sB = __shfl(rB.x, idx);
            float wB = __shfl(wBf, idx);
            if (idx >= mA) wA = 0.f;
            if (idx >= mB) wB = 0.f;
            ushort4 hA = *(const ushort4*)(H + (size_t)sA * 64 + c4);
            ushort4 hB = *(const ushort4*)(H + (size_t)sB * 64 + c4);
            a0 = fmaf(wA, bf2f(hA.x), a0);
            a1 = fmaf(wA, bf2f(hA.y), a1);
            a2 = fmaf(wA, bf2f(hA.z), a2);
            a3 = fmaf(wA, bf2f(hA.w), a3);
            b0 = fmaf(wB, bf2f(hB.x), b0);
            b1 = fmaf(wB, bf2f(hB.y), b1);
            b2 = fmaf(wB, bf2f(hB.z), b2);
            b3 = fmaf(wB, bf2f(hB.w), b3);
        }
        baseA += 64;
        baseB += 64;
    }
    // reduce across the 4 groups (lanes l, l+16, l+32, l+48)
    a0 += __shfl_down(a0, 32); a1 += __shfl_down(a1, 32);
    a2 += __shfl_down(a2, 32); a3 += __shfl_down(a3, 32);
    b0 += __shfl_down(b0, 32); b1 += __shfl_down(b1, 32);
    b2 += __shfl_down(b2, 32); b3 += __shfl_down(b3, 32);
    a0 += __shfl_down(a0, 16); a1 += __shfl_down(a1, 16);
    a2 += __shfl_down(a2, 16); a3 += __shfl_down(a3, 16);
    b0 += __shfl_down(b0, 16); b1 += __shfl_down(b1, 16);
    b2 += __shfl_down(b2, 16); b3 += __shfl_down(b3, 16);

    if (lane < 16) {
        float4 bv = *(const float4*)(bias + c4);
        float vA0 = a0 + bv.x, vA1 = a1 + bv.y, vA2 = a2 + bv.z, vA3 = a3 + bv.w;
        float vB0 = b0 + bv.x, vB1 = b1 + bv.y, vB2 = b2 + bv.z, vB3 = b3 + bv.w;
        if (RELU) {
            vA0 = fmaxf(vA0, 0.f); vA1 = fmaxf(vA1, 0.f);
            vA2 = fmaxf(vA2, 0.f); vA3 = fmaxf(vA3, 0.f);
            vB0 = fmaxf(vB0, 0.f); vB1 = fmaxf(vB1, 0.f);
            vB2 = fmaxf(vB2, 0.f); vB3 = fmaxf(vB3, 0.f);
        }
        if (OUT_BF16) {
            *(ushort4*)((ushort_t*)out + (size_t)n0 * 64 + c4) =
                make_ushort4(f2bf(vA0), f2bf(vA1), f2bf(vA2), f2bf(vA3));
            *(ushort4*)((ushort_t*)out + (size_t)n1 * 64 + c4) =
                make_ushort4(f2bf(vB0), f2bf(vB1), f2bf(vB2), f2bf(vB3));
        } else {
            *(float4*)((float*)out + (size_t)n0 * 64 + c4) =
                make_float4(vA0, vA1, vA2, vA3);
            *(float4*)((float*)out + (size_t)n1 * 64 + c4) =
                make_float4(vB0, vB1, vB2, vB3);
        }
    }
}

// ---------------------------------------------------------------------------
extern "C" void kernel_launch(void* const* d_in, const int* in_sizes, int n_in,
                              void* d_out, int out_size, void* d_ws, size_t ws_size,
                              hipStream_t stream) {
    const float* x   = (const float*)d_in[0];
    const int*   ei  = (const int*)  d_in[1];
    const float* ew  = (const float*)d_in[2];
    const float* w1  = (const float*)d_in[3];
    const float* b1  = (const float*)d_in[4];
    const float* w2  = (const float*)d_in[5];
    const float* b2  = (const float*)d_in[6];
    float* out = (float*)d_out;

    const int N = N_NODES, E = N_EDGES;
    const int* src = ei;
    const int* dst = ei + E;

    char* p = (char*)d_ws;
    ushort_t* bufA   = (ushort_t*)p;  p += (size_t)N_NODES * 64 * 2;   // 12.8MB: h1 / h2
    int2*     recs2  = (int2*)p;      p += (size_t)NB1 * CAP1 * 8;     // 14.7MB: exact CSR
    // recs1 (pass-1 output) aliases bufB: recs1 dead after k_pass2, which
    // completes before k_gather writes bufB (stream-ordered).
    int2*     recs1  = (int2*)p;
    ushort_t* bufB   = (ushort_t*)p;  p += (size_t)NB1 * CAP1 * 8;     // 14.7MB
    int*      gcur   = (int*)p;       p += 2048;
    int2*     ninfo  = (int2*)p;      p += (size_t)N_NODES * 8;        // 0.8MB

    // ---- single-pass bucket sort to exact CSR
    k_init <<<1, 512, 0, stream>>>(gcur);
    k_pass1<<<NT1, 512, 0, stream>>>(src, dst, ew, gcur, recs1, E);
    k_pass2<<<NB1, 256, 0, stream>>>(recs1, gcur, recs2, ninfo, N);

    // ---- layer 1
    k_gemm1<<<(N + 63) / 64, 256, 0, stream>>>(x, w1, bufA, N);
    k_gather<true, true><<<N / 8, 256, 0, stream>>>(bufA, recs2, ninfo, b1, bufB);

    // ---- layer 2
    k_gemm2<<<(N + 63) / 64, 256, 0, stream>>>(bufB, w2, bufA, N);
    k_gather<false, false><<<N / 8, 256, 0, stream>>>(bufA, recs2, ninfo, b2, out);
}